// Round 8
// baseline (30303.461 us; speedup 1.0000x reference)
//
#include <hip/hip_runtime.h>

#define H_  1024
#define B_  8
#define T_  2048
#define V_  256
#define NWG 256
#define NTH 512
#define NGRP 8
#define NRANK 32
#define WPG 256            // u64 words per h snapshot (1024 units / 4)

typedef unsigned long long u64;
typedef unsigned u32;

__device__ __forceinline__ u64 agload64(const u64* p) {
  return __hip_atomic_load(p, __ATOMIC_RELAXED, __HIP_MEMORY_SCOPE_AGENT);
}
__device__ __forceinline__ void agstore64(u64* p, u64 v) {
  __hip_atomic_store(p, v, __ATOMIC_RELAXED, __HIP_MEMORY_SCOPE_AGENT);
}
// full-precision bf16, RNE
__device__ __forceinline__ u32 f2bf(float f) {
  u32 u = __builtin_bit_cast(u32, f);
  return (u + 0x7fffu + ((u >> 16) & 1u)) >> 16;
}
// bf16 rounded (RNE) to 4-ULP grid: 2 LSBs free for the tag
__device__ __forceinline__ u32 f2bf14(float f) {
  u32 u = __builtin_bit_cast(u32, f);
  return ((u + 0x1FFFFu + ((u >> 18) & 1u)) >> 18) << 2;
}
__device__ __forceinline__ float bflo(u32 w) {   // low bf16 -> f32
  return __builtin_bit_cast(float, w << 16);
}
__device__ __forceinline__ float bfhi(u32 w) {   // high bf16 -> f32
  return __builtin_bit_cast(float, w & 0xFFFF0000u);
}

__global__ __launch_bounds__(NTH, 2)
void charrnn_lstm(const int* __restrict__ Xs, const int* __restrict__ ys,
                  const float* __restrict__ W_ih, const float* __restrict__ W_hh,
                  const float* __restrict__ b_ih, const float* __restrict__ b_hh,
                  const float* __restrict__ W1, const float* __restrict__ b1,
                  float* __restrict__ out, u64* __restrict__ hg64)
{
  // 8 groups x 32 WGs; group g owns batch g; each WG owns 32 h-units
  // (128 gate rows) of its batch. W_hh slice: bf16-packed, 128 VGPRs/thread.
  // LDS ~11 KB. Transport: per-group tagged-u64 all-gather (1 word/thread).
  __shared__ float hstage[4 * 264];   // h(t-1), f32, seg-padded (264 = 256+8)
  __shared__ float stash[H_];
  __shared__ float logits_s[V_];
  __shared__ float gates_s[128];
  __shared__ float c_s[NRANK];

  const int wg   = blockIdx.x;
  const int tid  = threadIdx.x;
  const int g    = wg & 7;          // group == batch == (likely) XCD
  const int rank = wg >> 3;         // 0..31 within group
  const int slot = rank;            // t%32 loss-position slot
  const int r_loc = tid >> 2;       // 0..127 local gate row
  const int seg   = tid & 3;        // k-segment (256 elems each)
  const int g4    = r_loc >> 5;     // gate 0..3 (i,f,g,o)
  const int u_loc = r_loc & 31;     // unit within this WG
  const int rg    = g4 * H_ + rank * NRANK + u_loc;   // global gate row

  u64* gbuf = hg64 + (size_t)g * (2 * WPG);   // this group's double buffer

  // ---- W_hh slice -> bf16-packed registers: 128 u32 per thread ----
  u32 wp[128];
  #pragma unroll
  for (int q = 0; q < 64; ++q) {
    const float4 w4 = *(const float4*)&W_hh[(size_t)rg * H_ + seg * 256 + q * 4];
    wp[2 * q]     = f2bf(w4.x) | (f2bf(w4.y) << 16);
    wp[2 * q + 1] = f2bf(w4.z) | (f2bf(w4.w) << 16);
  }
  const float breg = b_ih[rg] + b_hh[rg];
  if (tid < NRANK) c_s[tid] = 0.f;

  // rolling one-hot input-projection prefetch (x-col for step t)
  float xv = W_ih[(size_t)rg * V_ + Xs[g * T_]];

  int   pending = 0, chunk = 0, ptau = 0;
  float wg_loss = 0.f;

  auto do_chunk = [&]() {   // 1/32 slice of output-projection + CE for (g, ptau)
    const int v_loc = tid >> 6, lane64 = tid & 63;
    const int vg = chunk * 8 + v_loc;
    const float* wrow = &W1[(size_t)vg * H_];
    float4 la = make_float4(0.f, 0.f, 0.f, 0.f);
    #pragma unroll
    for (int j = 0; j < 4; ++j) {
      const int k0 = lane64 * 4 + j * 256;
      const float4 w4 = *(const float4*)&wrow[k0];
      const float4 h4 = *(const float4*)&stash[k0];
      la.x = fmaf(w4.x, h4.x, la.x);
      la.y = fmaf(w4.y, h4.y, la.y);
      la.z = fmaf(w4.z, h4.z, la.z);
      la.w = fmaf(w4.w, h4.w, la.w);
    }
    float l = (la.x + la.y) + (la.z + la.w);
    #pragma unroll
    for (int m = 1; m < 64; m <<= 1) l += __shfl_xor(l, m, 64);
    if (lane64 == 0) logits_s[vg] = l + b1[vg];
    chunk++;
    if (chunk == 32) {
      __syncthreads();
      if (tid < 64) {
        float mx = -3.4e38f;
        #pragma unroll
        for (int i2 = 0; i2 < 4; ++i2) mx = fmaxf(mx, logits_s[tid * 4 + i2]);
        #pragma unroll
        for (int m = 1; m < 64; m <<= 1) mx = fmaxf(mx, __shfl_xor(mx, m, 64));
        float se = 0.f;
        #pragma unroll
        for (int i2 = 0; i2 < 4; ++i2) se += __expf(logits_s[tid * 4 + i2] - mx);
        #pragma unroll
        for (int m = 1; m < 64; m <<= 1) se += __shfl_xor(se, m, 64);
        if (tid == 0) {
          const float ly = logits_s[ys[g * T_ + ptau]];
          wg_loss += -(ly - mx - __logf(se));
        }
      }
      pending = 0;
      chunk = 0;
      __syncthreads();
    }
  };

  __syncthreads();

  for (int t = 0; t < T_; ++t) {
    // ---- 1. tag-poll h(t-1) of OUR batch: 1 u64/thread (tid<256) ----
    const u64* hb = gbuf + ((t + 1) & 1) * WPG;
    const u32 tagp = (u32)t & 3u;
    if (tid < WPG) {
      u64 v;
      do { v = agload64(&hb[tid]); } while (((u32)v & 3u) != tagp);
      const u32 lo = (u32)v, hi = (u32)(v >> 32);
      float4 f;
      f.x = __builtin_bit_cast(float, (lo & 0xFFFCu) << 16);  // tag masked
      f.y = __builtin_bit_cast(float, lo & 0xFFFF0000u);
      f.z = __builtin_bit_cast(float, (hi & 0xFFFFu) << 16);
      f.w = __builtin_bit_cast(float, hi & 0xFFFF0000u);
      *(float4*)&hstage[(tid >> 6) * 264 + ((4 * tid) & 255)] = f;
    }
    // prefetch next step's one-hot column value (hidden under dot phase)
    const int cnext = Xs[g * T_ + ((t + 1 < T_) ? t + 1 : T_ - 1)];
    const float xv_next = W_ih[(size_t)rg * V_ + cnext];
    __syncthreads();   // B1: hstage ready

    // ---- 2. gate dot: row r_loc, k-seg seg; bf16 weights unpacked on the fly ----
    const float* hseg = &hstage[seg * 264];
    float a0 = 0.f, a1 = 0.f;
    #pragma unroll
    for (int q = 0; q < 64; ++q) {
      const float4 h4 = *(const float4*)&hseg[q * 4];
      const u32 wa = wp[2 * q], wb = wp[2 * q + 1];
      a0 = fmaf(bflo(wa), h4.x, a0);
      a1 = fmaf(bfhi(wa), h4.y, a1);
      a0 = fmaf(bflo(wb), h4.z, a0);
      a1 = fmaf(bfhi(wb), h4.w, a1);
    }
    float p = a0 + a1;
    p += __shfl_xor(p, 1, 64);
    p += __shfl_xor(p, 2, 64);
    if (seg == 0) gates_s[r_loc] = p + xv + breg;
    __syncthreads();   // B2: gates ready

    // ---- 3. c/h update (unit u = tid) + tagged u64 store (8 words/WG) ----
    if (tid < NRANK) {
      const int u = tid;
      float iv = gates_s[u],      fv = gates_s[32 + u];
      float gv = gates_s[64 + u], ov = gates_s[96 + u];
      iv = 1.f / (1.f + __expf(-iv));
      fv = 1.f / (1.f + __expf(-fv));
      gv = tanhf(gv);
      ov = 1.f / (1.f + __expf(-ov));
      const float c = fv * c_s[u] + iv * gv;
      c_s[u] = c;
      const float h = ov * tanhf(c);
      // unit u%4==0 carries the 2-bit tag in its bf16 LSBs
      const u32 full = f2bf(h);
      const u32 tagd = f2bf14(h) | ((u32)(t + 1) & 3u);
      const u32 r16 = ((u & 3) == 0) ? tagd : full;
      const u32 v0 = (u32)__shfl((int)r16, 4 * tid,     64);
      const u32 v1 = (u32)__shfl((int)r16, 4 * tid + 1, 64);
      const u32 v2 = (u32)__shfl((int)r16, 4 * tid + 2, 64);
      const u32 v3 = (u32)__shfl((int)r16, 4 * tid + 3, 64);
      if (tid < 8) {
        const u64 w = (u64)v0 | ((u64)v1 << 16) | ((u64)v2 << 32) | ((u64)v3 << 48);
        agstore64(&gbuf[(t & 1) * WPG + rank * 8 + tid], w);
      }
    }
    xv = xv_next;

    // ---- 4. stash h(tau) when this WG's loss slot comes up ----
    const int tau = t - 1;   // hstage holds h(t-1)
    const bool newst = (tau >= 0 && (tau & 31) == slot && !pending);
    if (newst) {
      const int i0 = tid, i1 = tid + 512;
      stash[i0] = hstage[(i0 >> 8) * 264 + (i0 & 255)];
      stash[i1] = hstage[(i1 >> 8) * 264 + (i1 & 255)];
    }
    if (newst) { pending = 1; chunk = 0; ptau = tau; }
    __syncthreads();   // B3: stash ready

    // ---- 5. fused-loss slice: hides under h-store visibility window ----
    if (pending) do_chunk();
  }

  // ---- drain in-flight loss position ----
  while (pending) do_chunk();

  // ---- tau = T-1 (rank 31): poll-decode final h of this batch ----
  if (slot == 31) {
    const u64* hb = gbuf + ((T_ - 1) & 1) * WPG;
    if (tid < WPG) {
      u64 v;
      do { v = agload64(&hb[tid]); } while (((u32)v & 3u) != ((u32)T_ & 3u));
      const u32 lo = (u32)v, hi = (u32)(v >> 32);
      float4 f;
      f.x = __builtin_bit_cast(float, (lo & 0xFFFCu) << 16);
      f.y = __builtin_bit_cast(float, lo & 0xFFFF0000u);
      f.z = __builtin_bit_cast(float, (hi & 0xFFFFu) << 16);
      f.w = __builtin_bit_cast(float, hi & 0xFFFF0000u);
      *(float4*)&stash[4 * tid] = f;
    }
    pending = 1; chunk = 0; ptau = T_ - 1;
    __syncthreads();
    while (pending) do_chunk();
  }

  if (tid == 0) atomicAdd(out, wg_loss * (1.0f / (B_ * T_)));
}

extern "C" void kernel_launch(void* const* d_in, const int* in_sizes, int n_in,
                              void* d_out, int out_size, void* d_ws, size_t ws_size,
                              hipStream_t stream) {
  const int*   Xs   = (const int*)d_in[0];
  const int*   ys   = (const int*)d_in[1];
  // d_in[2] = predict (always 0)
  const float* W_ih = (const float*)d_in[3];
  const float* W_hh = (const float*)d_in[4];
  const float* b_ih = (const float*)d_in[5];
  const float* b_hh = (const float*)d_in[6];
  const float* W1   = (const float*)d_in[7];
  const float* b1   = (const float*)d_in[8];
  float* out = (float*)d_out;

  u64* hg64 = (u64*)d_ws;   // [8 groups][2 slots][256 words]

  // replay-safe: zeroed buffer == h(-1)=0 with tag 0; zero loss accumulator
  hipMemsetAsync(d_out, 0, sizeof(float) * (size_t)out_size, stream);
  hipMemsetAsync(d_ws, 0, NGRP * 2 * WPG * sizeof(u64), stream);

  void* args[] = { (void*)&Xs, (void*)&ys, (void*)&W_ih, (void*)&W_hh,
                   (void*)&b_ih, (void*)&b_hh, (void*)&W1, (void*)&b1,
                   (void*)&out, (void*)&hg64 };
  hipError_t e = hipLaunchCooperativeKernel((const void*)charrnn_lstm, dim3(NWG),
                                            dim3(NTH), args, 0, stream);
  if (e != hipSuccess) {
    hipLaunchKernelGGL(charrnn_lstm, dim3(NWG), dim3(NTH), 0, stream,
                       Xs, ys, W_ih, W_hh, b_ih, b_hh, W1, b1, out, hg64);
  }
}

// Round 9
// 28875.555 us; speedup vs baseline: 1.0495x; 1.0495x over previous
//
#include <hip/hip_runtime.h>

#define H_  1024
#define B_  8
#define T_  2048
#define V_  256
#define NWG 256
#define NTH 512
#define NGRP 8
#define NRANK 32
#define WPG 256            // u64 words per h snapshot (1024 units / 4)

// workspace layout (bytes)
#define OFF_LOGITS 0u            // [B*T][V] fp32 = 16 MB
#define OFF_WIB    (16u << 20)   // [4H][V] bf16  =  2 MB
#define OFF_TRANS  (18u << 20)   // [NGRP][2][WPG] u64 = 32 KB

typedef unsigned long long u64;
typedef unsigned u32;
typedef unsigned short u16;

__device__ __forceinline__ u64 agload64(const u64* p) {
  return __hip_atomic_load(p, __ATOMIC_RELAXED, __HIP_MEMORY_SCOPE_AGENT);
}
__device__ __forceinline__ void agstore64(u64* p, u64 v) {
  __hip_atomic_store(p, v, __ATOMIC_RELAXED, __HIP_MEMORY_SCOPE_AGENT);
}
__device__ __forceinline__ u32 f2bf(float f) {          // bf16, RNE
  u32 u = __builtin_bit_cast(u32, f);
  return (u + 0x7fffu + ((u >> 16) & 1u)) >> 16;
}
__device__ __forceinline__ u32 f2bf14(float f) {        // bf16 on 4-ULP grid
  u32 u = __builtin_bit_cast(u32, f);
  return ((u + 0x1FFFFu + ((u >> 18) & 1u)) >> 18) << 2;
}
__device__ __forceinline__ float bflo(u32 w) { return __builtin_bit_cast(float, w << 16); }
__device__ __forceinline__ float bfhi(u32 w) { return __builtin_bit_cast(float, w & 0xFFFF0000u); }

// ---- prep: W_ih fp32 -> bf16 (2 MB, L2-resident afterwards) ----
__global__ __launch_bounds__(256, 4)
void prep_wih(const float* __restrict__ W_ih, u32* __restrict__ Wib32) {
  const int i = blockIdx.x * 256 + threadIdx.x;   // 131072 threads x 8 elems
  const int e0 = i * 8;
  const float4 a = *(const float4*)&W_ih[e0];
  const float4 b = *(const float4*)&W_ih[e0 + 4];
  Wib32[i * 4 + 0] = f2bf(a.x) | (f2bf(a.y) << 16);
  Wib32[i * 4 + 1] = f2bf(a.z) | (f2bf(a.w) << 16);
  Wib32[i * 4 + 2] = f2bf(b.x) | (f2bf(b.y) << 16);
  Wib32[i * 4 + 3] = f2bf(b.z) | (f2bf(b.w) << 16);
}

// ---- main persistent recurrence (cooperative): 8 groups x 32 WGs ----
__global__ __launch_bounds__(NTH, 2)
void charrnn_lstm(const int* __restrict__ Xs, const float* __restrict__ W_hh,
                  const float* __restrict__ b_ih, const float* __restrict__ b_hh,
                  const float* __restrict__ W1, const u16* __restrict__ Wib,
                  float* __restrict__ logits, u64* __restrict__ hg64)
{
  __shared__ float hstage[4 * 264];   // h(t-1) f32, seg-padded
  __shared__ float gates_s[128];
  __shared__ float c_s[NRANK];
  __shared__ int   xrow[T_];          // this batch's full char row (8 KB)

  const int wg   = blockIdx.x;
  const int tid  = threadIdx.x;
  const int g    = wg & 7;          // group == batch
  const int rank = wg >> 3;         // 0..31 within group
  const int r_loc = tid >> 2;       // 0..127 local gate row
  const int seg   = tid & 3;        // k-segment (256 elems)
  const int g4    = r_loc >> 5;     // gate 0..3 (i,f,g,o)
  const int u_loc = r_loc & 31;     // unit within this WG
  const int rg    = g4 * H_ + rank * NRANK + u_loc;   // global gate row
  const int lane64 = tid & 63, v_loc = tid >> 6;
  const int vg     = rank * 8 + v_loc;                // this WG's fixed logit rows

  u64* gbuf = hg64 + (size_t)g * (2 * WPG);

  // W_hh slice -> bf16-packed registers (128 u32/thread)
  u32 wp[128];
  #pragma unroll
  for (int q = 0; q < 64; ++q) {
    const float4 w4 = *(const float4*)&W_hh[(size_t)rg * H_ + seg * 256 + q * 4];
    wp[2 * q]     = f2bf(w4.x) | (f2bf(w4.y) << 16);
    wp[2 * q + 1] = f2bf(w4.z) | (f2bf(w4.w) << 16);
  }
  const float breg = b_ih[rg] + b_hh[rg];
  if (tid < NRANK) c_s[tid] = 0.f;
  for (int i = tid; i < T_; i += NTH) xrow[i] = Xs[g * T_ + i];
  __syncthreads();
  float xv = bflo((u32)Wib[rg * V_ + xrow[0]]);

  // poll h(tt-1): buffer (tt+1)&1, tag tt&3 (tag = 2 LSBs of unit-0 bf16)
  auto poll_decode = [&](int tt) {
    const u64* hb = gbuf + ((tt + 1) & 1) * WPG;
    const u32 tagp = (u32)tt & 3u;
    if (tid < WPG) {
      u64 v;
      do { v = agload64(&hb[tid]); } while (((u32)v & 3u) != tagp);
      const u32 lo = (u32)v, hi = (u32)(v >> 32);
      float4 f;
      f.x = __builtin_bit_cast(float, (lo & 0xFFFCu) << 16);
      f.y = __builtin_bit_cast(float, lo & 0xFFFF0000u);
      f.z = __builtin_bit_cast(float, (hi & 0xFFFFu) << 16);
      f.w = __builtin_bit_cast(float, hi & 0xFFFF0000u);
      *(float4*)&hstage[(tid >> 6) * 264 + ((4 * tid) & 255)] = f;
    }
  };

  // fixed-rank logit slice for position tau (h(tau) must be in hstage)
  auto do_logit = [&](int tau) {
    const float* wrow = &W1[(size_t)vg * H_];
    float4 la = make_float4(0.f, 0.f, 0.f, 0.f);
    #pragma unroll
    for (int j = 0; j < 4; ++j) {
      const float4 w4 = *(const float4*)&wrow[lane64 * 4 + j * 256];
      const float4 h4 = *(const float4*)&hstage[j * 264 + lane64 * 4];
      la.x = fmaf(w4.x, h4.x, la.x);
      la.y = fmaf(w4.y, h4.y, la.y);
      la.z = fmaf(w4.z, h4.z, la.z);
      la.w = fmaf(w4.w, h4.w, la.w);
    }
    float l = (la.x + la.y) + (la.z + la.w);
    #pragma unroll
    for (int m = 1; m < 64; m <<= 1) l += __shfl_xor(l, m, 64);
    if (lane64 == 0) logits[((size_t)g * T_ + tau) * V_ + vg] = l;
  };

  for (int t = 0; t < T_; ++t) {
    // prefetch next step's one-hot column value (L2 hit, hidden under step)
    const int cn = xrow[(t + 1 < T_) ? t + 1 : T_ - 1];
    const float xv_next = bflo((u32)Wib[rg * V_ + cn]);

    poll_decode(t);
    __syncthreads();   // B1: hstage = h(t-1)

    if (t > 0) do_logit(t - 1);   // off-critical-path, W1 slice L2-resident

    // gate dot: row r_loc, k-seg seg
    const float* hseg = &hstage[seg * 264];
    float a0 = 0.f, a1 = 0.f;
    #pragma unroll
    for (int q = 0; q < 64; ++q) {
      const float4 h4 = *(const float4*)&hseg[q * 4];
      const u32 wa = wp[2 * q], wb = wp[2 * q + 1];
      a0 = fmaf(bflo(wa), h4.x, a0);
      a1 = fmaf(bfhi(wa), h4.y, a1);
      a0 = fmaf(bflo(wb), h4.z, a0);
      a1 = fmaf(bfhi(wb), h4.w, a1);
    }
    float p = a0 + a1;
    p += __shfl_xor(p, 1, 64);
    p += __shfl_xor(p, 2, 64);
    if (seg == 0) gates_s[r_loc] = p + xv + breg;
    __syncthreads();   // B2: gates ready; all hstage reads done

    if (tid < NRANK) {
      const int u = tid;
      float iv = gates_s[u],      fv = gates_s[32 + u];
      float gv = gates_s[64 + u], ov = gates_s[96 + u];
      iv = 1.f / (1.f + __expf(-iv));
      fv = 1.f / (1.f + __expf(-fv));
      gv = tanhf(gv);
      ov = 1.f / (1.f + __expf(-ov));
      const float c = fv * c_s[u] + iv * gv;
      c_s[u] = c;
      const float h = ov * tanhf(c);
      const u32 full = f2bf(h);
      const u32 tagd = f2bf14(h) | ((u32)(t + 1) & 3u);
      const u32 r16 = ((u & 3) == 0) ? tagd : full;
      const u32 v0 = (u32)__shfl((int)r16, 4 * tid,     64);
      const u32 v1 = (u32)__shfl((int)r16, 4 * tid + 1, 64);
      const u32 v2 = (u32)__shfl((int)r16, 4 * tid + 2, 64);
      const u32 v3 = (u32)__shfl((int)r16, 4 * tid + 3, 64);
      if (tid < 8) {
        const u64 w = (u64)v0 | ((u64)v1 << 16) | ((u64)v2 << 32) | ((u64)v3 << 48);
        agstore64(&gbuf[(t & 1) * WPG + rank * 8 + tid], w);
      }
    }
    xv = xv_next;
  }

  // final position: h(T-1) -> logits[.., T-1, ..]
  poll_decode(T_);
  __syncthreads();
  do_logit(T_ - 1);
}

// ---- deferred softmax + NLL + mean ----
__global__ __launch_bounds__(256, 4)
void loss_kernel(const int* __restrict__ ys, const float* __restrict__ b1,
                 const float* __restrict__ logits, float* __restrict__ out) {
  const int wave = threadIdx.x >> 6, lane = threadIdx.x & 63;
  const int base = blockIdx.x * 64 + wave * 16;
  const float4 bb = *(const float4*)&b1[lane * 4];
  float acc = 0.f;
  for (int i = 0; i < 16; ++i) {
    const int pos = base + i;
    float4 la = *(const float4*)&logits[(size_t)pos * V_ + lane * 4];
    la.x += bb.x; la.y += bb.y; la.z += bb.z; la.w += bb.w;
    float mx = fmaxf(fmaxf(la.x, la.y), fmaxf(la.z, la.w));
    #pragma unroll
    for (int m = 1; m < 64; m <<= 1) mx = fmaxf(mx, __shfl_xor(mx, m, 64));
    float se = __expf(la.x - mx) + __expf(la.y - mx) +
               __expf(la.z - mx) + __expf(la.w - mx);
    #pragma unroll
    for (int m = 1; m < 64; m <<= 1) se += __shfl_xor(se, m, 64);
    const int col = ys[pos];            // pos = b*T + t matches ys layout
    const int s = col & 3;
    const float cand = (s == 0) ? la.x : (s == 1) ? la.y : (s == 2) ? la.z : la.w;
    const float ly = __shfl(cand, col >> 2, 64);
    acc += -(ly - mx - __logf(se));
  }
  if (lane == 0) atomicAdd(out, acc * (1.0f / (B_ * T_)));
}

extern "C" void kernel_launch(void* const* d_in, const int* in_sizes, int n_in,
                              void* d_out, int out_size, void* d_ws, size_t ws_size,
                              hipStream_t stream) {
  const int*   Xs   = (const int*)d_in[0];
  const int*   ys   = (const int*)d_in[1];
  // d_in[2] = predict (always 0)
  const float* W_ih = (const float*)d_in[3];
  const float* W_hh = (const float*)d_in[4];
  const float* b_ih = (const float*)d_in[5];
  const float* b_hh = (const float*)d_in[6];
  const float* W1   = (const float*)d_in[7];
  const float* b1   = (const float*)d_in[8];
  float* out = (float*)d_out;

  float* logits = (float*)((char*)d_ws + OFF_LOGITS);
  u16*   Wib    = (u16*)((char*)d_ws + OFF_WIB);
  u64*   hg64   = (u64*)((char*)d_ws + OFF_TRANS);

  // replay-safe: zero loss accumulator + transport tags (tag0 == h(-1)=0)
  hipMemsetAsync(d_out, 0, sizeof(float) * (size_t)out_size, stream);
  hipMemsetAsync(hg64, 0, NGRP * 2 * WPG * sizeof(u64), stream);

  prep_wih<<<512, 256, 0, stream>>>(W_ih, (u32*)Wib);

  void* args[] = { (void*)&Xs, (void*)&W_hh, (void*)&b_ih, (void*)&b_hh,
                   (void*)&W1, (void*)&Wib, (void*)&logits, (void*)&hg64 };
  hipError_t e = hipLaunchCooperativeKernel((const void*)charrnn_lstm, dim3(NWG),
                                            dim3(NTH), args, 0, stream);
  if (e != hipSuccess) {
    hipLaunchKernelGGL(charrnn_lstm, dim3(NWG), dim3(NTH), 0, stream,
                       Xs, W_hh, b_ih, b_hh, W1, Wib, logits, hg64);
  }

  loss_kernel<<<256, 256, 0, stream>>>(ys, b1, logits, out);
}

// Round 10
// 28770.438 us; speedup vs baseline: 1.0533x; 1.0037x over previous
//
#include <hip/hip_runtime.h>

#define H_  1024
#define B_  8
#define T_  2048
#define V_  256
#define NWG 256
#define NTH 512
#define NGRP 8
#define NRANK 32
#define WPG 256            // u64 words per h snapshot (1024 units / 4)

// workspace layout (bytes)
#define OFF_LOGITS 0u            // [B*T][V] fp32 = 16 MB
#define OFF_WIB    (16u << 20)   // [4H][V] bf16  =  2 MB
#define OFF_TRANS  (18u << 20)   // [NGRP][2][WPG] u64 = 32 KB

typedef unsigned long long u64;
typedef unsigned u32;
typedef unsigned short u16;

__device__ __forceinline__ u64 agload64(const u64* p) {
  return __hip_atomic_load(p, __ATOMIC_RELAXED, __HIP_MEMORY_SCOPE_AGENT);
}
__device__ __forceinline__ void agstore64(u64* p, u64 v) {
  __hip_atomic_store(p, v, __ATOMIC_RELAXED, __HIP_MEMORY_SCOPE_AGENT);
}
__device__ __forceinline__ u32 f2bf(float f) {          // bf16, RNE
  u32 u = __builtin_bit_cast(u32, f);
  return (u + 0x7fffu + ((u >> 16) & 1u)) >> 16;
}
__device__ __forceinline__ u32 f2bf14(float f) {        // bf16 on 4-ULP grid
  u32 u = __builtin_bit_cast(u32, f);
  return ((u + 0x1FFFFu + ((u >> 18) & 1u)) >> 18) << 2;
}
__device__ __forceinline__ float bflo(u32 w) { return __builtin_bit_cast(float, w << 16); }
__device__ __forceinline__ float bfhi(u32 w) { return __builtin_bit_cast(float, w & 0xFFFF0000u); }

// ---- prep: W_ih fp32 -> bf16 (2 MB, L2-resident afterwards) ----
__global__ __launch_bounds__(256, 4)
void prep_wih(const float* __restrict__ W_ih, u32* __restrict__ Wib32) {
  const int i = blockIdx.x * 256 + threadIdx.x;   // 131072 threads x 8 elems
  const int e0 = i * 8;
  const float4 a = *(const float4*)&W_ih[e0];
  const float4 b = *(const float4*)&W_ih[e0 + 4];
  Wib32[i * 4 + 0] = f2bf(a.x) | (f2bf(a.y) << 16);
  Wib32[i * 4 + 1] = f2bf(a.z) | (f2bf(a.w) << 16);
  Wib32[i * 4 + 2] = f2bf(b.x) | (f2bf(b.y) << 16);
  Wib32[i * 4 + 3] = f2bf(b.z) | (f2bf(b.w) << 16);
}

// ---- main persistent recurrence (cooperative): 8 groups x 32 WGs ----
__global__ __launch_bounds__(NTH, 2)
void charrnn_lstm(const int* __restrict__ Xs, const float* __restrict__ W_hh,
                  const float* __restrict__ b_ih, const float* __restrict__ b_hh,
                  const float* __restrict__ W1, const u16* __restrict__ Wib,
                  float* __restrict__ logits, u64* __restrict__ hg64)
{
  __shared__ float hstage[4 * 264];   // h(t-1) f32, seg-padded
  __shared__ float gates_s[128];
  __shared__ float c_s[NRANK];
  __shared__ int   xrow[T_];          // this batch's full char row (8 KB)

  const int wg   = blockIdx.x;
  const int tid  = threadIdx.x;
  const int g    = wg & 7;          // group == batch
  const int rank = wg >> 3;         // 0..31 within group
  const int r_loc = tid >> 2;       // 0..127 local gate row
  const int seg   = tid & 3;        // k-segment (256 elems)
  const int g4    = r_loc >> 5;     // gate 0..3 (i,f,g,o)
  const int u_loc = r_loc & 31;     // unit within this WG
  const int rg    = g4 * H_ + rank * NRANK + u_loc;   // global gate row
  const int lane64 = tid & 63, v_loc = tid >> 6;
  const int vg     = rank * 8 + v_loc;                // this WG's fixed logit rows

  u64* gbuf = hg64 + (size_t)g * (2 * WPG);

  // W_hh slice -> bf16-packed registers (128 u32/thread)
  u32 wp[128];
  #pragma unroll
  for (int q = 0; q < 64; ++q) {
    const float4 w4 = *(const float4*)&W_hh[(size_t)rg * H_ + seg * 256 + q * 4];
    wp[2 * q]     = f2bf(w4.x) | (f2bf(w4.y) << 16);
    wp[2 * q + 1] = f2bf(w4.z) | (f2bf(w4.w) << 16);
  }
  const float breg = b_ih[rg] + b_hh[rg];
  if (tid < NRANK) c_s[tid] = 0.f;
  for (int i = tid; i < T_; i += NTH) xrow[i] = Xs[g * T_ + i];
  __syncthreads();
  float xv = bflo((u32)Wib[rg * V_ + xrow[0]]);

  // poll h(tt-1): buffer (tt+1)&1, tag tt&3 (tag = 2 LSBs of unit-0 bf16).
  // s_sleep backoff is ESSENTIAL: unthrottled agent-scope spin loads from
  // 8192 threads congest the coherence fabric and ~4x the visibility latency
  // (rounds 8/9 regression: 30 ms, 9-13 GB FETCH of pure spin traffic).
  auto poll_decode = [&](int tt) {
    const u64* hb = gbuf + ((tt + 1) & 1) * WPG;
    const u32 tagp = (u32)tt & 3u;
    if (tid < WPG) {
      u64 v = agload64(&hb[tid]);
      while (((u32)v & 3u) != tagp) {
        __builtin_amdgcn_s_sleep(1);
        v = agload64(&hb[tid]);
      }
      const u32 lo = (u32)v, hi = (u32)(v >> 32);
      float4 f;
      f.x = __builtin_bit_cast(float, (lo & 0xFFFCu) << 16);
      f.y = __builtin_bit_cast(float, lo & 0xFFFF0000u);
      f.z = __builtin_bit_cast(float, (hi & 0xFFFFu) << 16);
      f.w = __builtin_bit_cast(float, hi & 0xFFFF0000u);
      *(float4*)&hstage[(tid >> 6) * 264 + ((4 * tid) & 255)] = f;
    }
  };

  // fixed-rank logit slice for position tau (h(tau) must be in hstage)
  auto do_logit = [&](int tau) {
    const float* wrow = &W1[(size_t)vg * H_];
    float4 la = make_float4(0.f, 0.f, 0.f, 0.f);
    #pragma unroll
    for (int j = 0; j < 4; ++j) {
      const float4 w4 = *(const float4*)&wrow[lane64 * 4 + j * 256];
      const float4 h4 = *(const float4*)&hstage[j * 264 + lane64 * 4];
      la.x = fmaf(w4.x, h4.x, la.x);
      la.y = fmaf(w4.y, h4.y, la.y);
      la.z = fmaf(w4.z, h4.z, la.z);
      la.w = fmaf(w4.w, h4.w, la.w);
    }
    float l = (la.x + la.y) + (la.z + la.w);
    #pragma unroll
    for (int m = 1; m < 64; m <<= 1) l += __shfl_xor(l, m, 64);
    if (lane64 == 0) logits[((size_t)g * T_ + tau) * V_ + vg] = l;
  };

  for (int t = 0; t < T_; ++t) {
    // prefetch next step's one-hot column value (L2 hit, hidden under step)
    const int cn = xrow[(t + 1 < T_) ? t + 1 : T_ - 1];
    const float xv_next = bflo((u32)Wib[rg * V_ + cn]);

    poll_decode(t);
    __syncthreads();   // B1: hstage = h(t-1)

    if (t > 0) do_logit(t - 1);   // off-critical-path, W1 slice L2-resident

    // gate dot: row r_loc, k-seg seg
    const float* hseg = &hstage[seg * 264];
    float a0 = 0.f, a1 = 0.f;
    #pragma unroll
    for (int q = 0; q < 64; ++q) {
      const float4 h4 = *(const float4*)&hseg[q * 4];
      const u32 wa = wp[2 * q], wb = wp[2 * q + 1];
      a0 = fmaf(bflo(wa), h4.x, a0);
      a1 = fmaf(bfhi(wa), h4.y, a1);
      a0 = fmaf(bflo(wb), h4.z, a0);
      a1 = fmaf(bfhi(wb), h4.w, a1);
    }
    float p = a0 + a1;
    p += __shfl_xor(p, 1, 64);
    p += __shfl_xor(p, 2, 64);
    if (seg == 0) gates_s[r_loc] = p + xv + breg;
    __syncthreads();   // B2: gates ready; all hstage reads done

    if (tid < NRANK) {
      const int u = tid;
      float iv = gates_s[u],      fv = gates_s[32 + u];
      float gv = gates_s[64 + u], ov = gates_s[96 + u];
      iv = 1.f / (1.f + __expf(-iv));
      fv = 1.f / (1.f + __expf(-fv));
      gv = tanhf(gv);
      ov = 1.f / (1.f + __expf(-ov));
      const float c = fv * c_s[u] + iv * gv;
      c_s[u] = c;
      const float h = ov * tanhf(c);
      const u32 full = f2bf(h);
      const u32 tagd = f2bf14(h) | ((u32)(t + 1) & 3u);
      const u32 r16 = ((u & 3) == 0) ? tagd : full;
      const u32 v0 = (u32)__shfl((int)r16, 4 * tid,     64);
      const u32 v1 = (u32)__shfl((int)r16, 4 * tid + 1, 64);
      const u32 v2 = (u32)__shfl((int)r16, 4 * tid + 2, 64);
      const u32 v3 = (u32)__shfl((int)r16, 4 * tid + 3, 64);
      if (tid < 8) {
        const u64 w = (u64)v0 | ((u64)v1 << 16) | ((u64)v2 << 32) | ((u64)v3 << 48);
        agstore64(&gbuf[(t & 1) * WPG + rank * 8 + tid], w);
      }
    }
    xv = xv_next;
  }

  // final position: h(T-1) -> logits[.., T-1, ..]
  poll_decode(T_);
  __syncthreads();
  do_logit(T_ - 1);
}

// ---- deferred softmax + NLL + mean ----
__global__ __launch_bounds__(256, 4)
void loss_kernel(const int* __restrict__ ys, const float* __restrict__ b1,
                 const float* __restrict__ logits, float* __restrict__ out) {
  const int wave = threadIdx.x >> 6, lane = threadIdx.x & 63;
  const int base = blockIdx.x * 64 + wave * 16;
  const float4 bb = *(const float4*)&b1[lane * 4];
  float acc = 0.f;
  for (int i = 0; i < 16; ++i) {
    const int pos = base + i;
    float4 la = *(const float4*)&logits[(size_t)pos * V_ + lane * 4];
    la.x += bb.x; la.y += bb.y; la.z += bb.z; la.w += bb.w;
    float mx = fmaxf(fmaxf(la.x, la.y), fmaxf(la.z, la.w));
    #pragma unroll
    for (int m = 1; m < 64; m <<= 1) mx = fmaxf(mx, __shfl_xor(mx, m, 64));
    float se = __expf(la.x - mx) + __expf(la.y - mx) +
               __expf(la.z - mx) + __expf(la.w - mx);
    #pragma unroll
    for (int m = 1; m < 64; m <<= 1) se += __shfl_xor(se, m, 64);
    const int col = ys[pos];            // pos = b*T + t matches ys layout
    const int s = col & 3;
    const float cand = (s == 0) ? la.x : (s == 1) ? la.y : (s == 2) ? la.z : la.w;
    const float ly = __shfl(cand, col >> 2, 64);
    acc += -(ly - mx - __logf(se));
  }
  if (lane == 0) atomicAdd(out, acc * (1.0f / (B_ * T_)));
}

extern "C" void kernel_launch(void* const* d_in, const int* in_sizes, int n_in,
                              void* d_out, int out_size, void* d_ws, size_t ws_size,
                              hipStream_t stream) {
  const int*   Xs   = (const int*)d_in[0];
  const int*   ys   = (const int*)d_in[1];
  // d_in[2] = predict (always 0)
  const float* W_ih = (const float*)d_in[3];
  const float* W_hh = (const float*)d_in[4];
  const float* b_ih = (const float*)d_in[5];
  const float* b_hh = (const float*)d_in[6];
  const float* W1   = (const float*)d_in[7];
  const float* b1   = (const float*)d_in[8];
  float* out = (float*)d_out;

  float* logits = (float*)((char*)d_ws + OFF_LOGITS);
  u16*   Wib    = (u16*)((char*)d_ws + OFF_WIB);
  u64*   hg64   = (u64*)((char*)d_ws + OFF_TRANS);

  // replay-safe: zero loss accumulator + transport tags (tag0 == h(-1)=0)
  hipMemsetAsync(d_out, 0, sizeof(float) * (size_t)out_size, stream);
  hipMemsetAsync(hg64, 0, NGRP * 2 * WPG * sizeof(u64), stream);

  prep_wih<<<512, 256, 0, stream>>>(W_ih, (u32*)Wib);

  void* args[] = { (void*)&Xs, (void*)&W_hh, (void*)&b_ih, (void*)&b_hh,
                   (void*)&W1, (void*)&Wib, (void*)&logits, (void*)&hg64 };
  hipError_t e = hipLaunchCooperativeKernel((const void*)charrnn_lstm, dim3(NWG),
                                            dim3(NTH), args, 0, stream);
  if (e != hipSuccess) {
    hipLaunchKernelGGL(charrnn_lstm, dim3(NWG), dim3(NTH), 0, stream,
                       Xs, W_hh, b_ih, b_hh, W1, Wib, logits, hg64);
  }

  loss_kernel<<<256, 256, 0, stream>>>(ys, b1, logits, out);
}

// Round 11
// 16351.376 us; speedup vs baseline: 1.8533x; 1.7595x over previous
//
#include <hip/hip_runtime.h>

#define H_  1024
#define B_  8
#define T_  2048
#define V_  256
#define NWG 256
#define NTH 512
#define WPS (B_ * H_ / 4)   // 2048 u64 words per transport slot

// workspace layout (bytes)
#define OFF_TRANS 0u            // [2][WPS] u64 transport = 32 KB
#define OFF_PART  (64u << 10)   // [T_] f32 per-timestep partial NLL = 8 KB
#define OFF_HS    (1u << 20)    // [T_][B_][256] u64 tagged h = 32 MB

typedef unsigned long long u64;
typedef unsigned u32;

__device__ __forceinline__ u64 agload64(const u64* p) {
  return __hip_atomic_load(p, __ATOMIC_RELAXED, __HIP_MEMORY_SCOPE_AGENT);
}
__device__ __forceinline__ void agstore64(u64* p, u64 v) {
  __hip_atomic_store(p, v, __ATOMIC_RELAXED, __HIP_MEMORY_SCOPE_AGENT);
}
__device__ __forceinline__ u32 f2bf(float f) {          // bf16, RNE
  u32 u = __builtin_bit_cast(u32, f);
  return (u + 0x7fffu + ((u >> 16) & 1u)) >> 16;
}
__device__ __forceinline__ u32 f2bf14(float f) {        // bf16 on 4-ULP grid
  u32 u = __builtin_bit_cast(u32, f);
  return ((u + 0x1FFFFu + ((u >> 18) & 1u)) >> 18) << 2;
}

// decode one tagged u64 -> 4 f32 (unit-0 halfword's 2 tag LSBs masked)
__device__ __forceinline__ float4 dec4(u64 v) {
  const u32 lo = (u32)v, hi = (u32)(v >> 32);
  float4 f;
  f.x = __builtin_bit_cast(float, (lo & 0xFFFCu) << 16);
  f.y = __builtin_bit_cast(float, lo & 0xFFFF0000u);
  f.z = __builtin_bit_cast(float, (hi & 0xFFFFu) << 16);
  f.w = __builtin_bit_cast(float, hi & 0xFFFF0000u);
  return f;
}

// ---- main persistent recurrence: EXACT round-7 structure (global lockstep,
// tagged-u64 transport) minus the in-loop loss machinery (stash/do_chunk/B3).
__global__ __launch_bounds__(NTH, 1)
void charrnn_lstm(const int* __restrict__ Xs, const float* __restrict__ W_ih,
                  const float* __restrict__ W_hh, const float* __restrict__ b_ih,
                  const float* __restrict__ b_hh, u64* __restrict__ hg64,
                  u64* __restrict__ hs)
{
  __shared__ float hstage[B_][H_];   // 32 KB
  __shared__ float Wis[16][V_];      // 16 KB
  __shared__ float gates_s[16][8];
  __shared__ float c_s[4][8];
  __shared__ float bias_s[16];
  __shared__ int   xw[8][32];        // 32-step window of Xs

  const int wg   = blockIdx.x;
  const int tid  = threadIdx.x;
  const int b_g  = wg & 7;    // batch whose h this WG dumps
  const int slot = wg >> 3;   // t%32 dump slot
  const int row  = tid >> 5;  // 0..15 : local gate-row (gate*4 + jj)
  const int seg  = tid & 31;  // 0..31 : k-segment

  // W_hh slice -> registers: 32 floats/thread
  const int rg = (row >> 2) * H_ + wg * 4 + (row & 3);
  float4 wreg[8];
  #pragma unroll
  for (int q = 0; q < 8; ++q)
    wreg[q] = *(const float4*)&W_hh[(size_t)rg * H_ + seg * 4 + q * 128];

  // one-time W_ih slice -> LDS
  for (int i = tid; i < 16 * (V_ / 4); i += NTH) {
    int rl = i >> 6;
    int kq = i & 63;
    int rr = (rl >> 2) * H_ + wg * 4 + (rl & 3);
    *(float4*)&Wis[rl][kq * 4] = *(const float4*)&W_ih[(size_t)rr * V_ + kq * 4];
  }
  if (tid < 16) {
    int rr = (tid >> 2) * H_ + wg * 4 + (tid & 3);
    bias_s[tid] = b_ih[rr] + b_hh[rr];
  }
  if (tid < 32) c_s[tid >> 3][tid & 7] = 0.f;
  __syncthreads();

  for (int t = 0; t < T_; ++t) {
    // ---- 1. tag-poll stage of h(t-1): 4 x b64; tag = 2 LSBs of halfword 0 ----
    const u64* hb = hg64 + (size_t)((t + 1) & 1) * WPS;
    const u32 tagp = (u32)t & 3u;
    u64 v[4];
    for (;;) {
      bool ok = true;
      #pragma unroll
      for (int i = 0; i < 4; ++i) v[i] = agload64(&hb[i * NTH + tid]);
      #pragma unroll
      for (int i = 0; i < 4; ++i) ok &= (((u32)v[i] & 3u) == tagp);
      if (ok) break;
      __builtin_amdgcn_s_sleep(1);
    }
    // dump h(t-1) of batch b_g straight from poll VGPRs (fire-and-forget):
    // word idx = b*256+u4; for i=b_g>>1, threads with tid>>8 == b_g&1 hold batch b_g.
    if (t > 0 && ((t - 1) & 31) == slot && (tid >> 8) == (b_g & 1))
      hs[((size_t)(t - 1) * B_ + b_g) * 256 + (tid & 255)] = v[b_g >> 1];
    #pragma unroll
    for (int i = 0; i < 4; ++i) {
      const int idx = i * NTH + tid;          // word index 0..2047
      const int b = idx >> 8, u4 = idx & 255;
      *(float4*)&hstage[b][u4 * 4] = dec4(v[i]);
    }
    if ((t & 31) == 0 && tid < 256) {   // refresh 32-step Xs window
      const int b = tid >> 5, tt = t + (tid & 31);
      xw[b][tid & 31] = (tt < T_) ? Xs[b * T_ + tt] : 0;
    }
    __syncthreads();   // B1: hstage = h(t-1)

    // ---- 2. gate partial dots: thread (row, seg), 8 q-iters x 8 batches ----
    float4 acc[8];
    #pragma unroll
    for (int b = 0; b < 8; ++b) acc[b] = make_float4(0.f, 0.f, 0.f, 0.f);
    #pragma unroll
    for (int q = 0; q < 8; ++q) {
      const int k0 = seg * 4 + q * 128;
      const float4 w = wreg[q];
      #pragma unroll
      for (int b = 0; b < 8; ++b) {
        const float4 h4 = *(const float4*)&hstage[b][k0];
        acc[b].x = fmaf(w.x, h4.x, acc[b].x);
        acc[b].y = fmaf(w.y, h4.y, acc[b].y);
        acc[b].z = fmaf(w.z, h4.z, acc[b].z);
        acc[b].w = fmaf(w.w, h4.w, acc[b].w);
      }
    }
    float s[8];
    #pragma unroll
    for (int b = 0; b < 8; ++b) s[b] = (acc[b].x + acc[b].y) + (acc[b].z + acc[b].w);
    #pragma unroll
    for (int m = 1; m < 32; m <<= 1) {
      #pragma unroll
      for (int b = 0; b < 8; ++b) s[b] += __shfl_xor(s[b], m, 64);
    }
    if (seg < 8)   // b = seg
      gates_s[row][seg] = s[seg] + Wis[row][xw[seg][t & 31]] + bias_s[row];
    __syncthreads();   // B2: gates ready; all hstage reads done

    // ---- 3. c/h update + one u64 tagged store per batch (8 stores/WG) ----
    if (tid < 32) {
      const int jj = tid >> 3, b = tid & 7;
      float iv = gates_s[jj][b],      fv = gates_s[4 + jj][b];
      float gv = gates_s[8 + jj][b],  ov = gates_s[12 + jj][b];
      iv = 1.f / (1.f + __expf(-iv));
      fv = 1.f / (1.f + __expf(-fv));
      gv = tanhf(gv);
      ov = 1.f / (1.f + __expf(-ov));
      const float c = fv * c_s[jj][b] + iv * gv;
      c_s[jj][b] = c;
      const float h = ov * tanhf(c);
      const u32 full = f2bf(h);
      const u32 tagd = f2bf14(h) | ((u32)(t + 1) & 3u);
      const u32 r16 = ((jj & 3) == 0) ? tagd : full;   // jj==0 carries tag
      const u32 p1 = (u32)__shfl((int)r16, b + 8, 64);    // jj=1
      const u32 p2 = (u32)__shfl((int)r16, b + 16, 64);   // jj=2
      const u32 p3 = (u32)__shfl((int)r16, b + 24, 64);   // jj=3
      if (tid < 8) {
        const u64 w = (u64)r16 | ((u64)p1 << 16) | ((u64)p2 << 32) | ((u64)p3 << 48);
        agstore64(&hg64[(size_t)(t & 1) * WPS + tid * 256 + wg], w);
      }
    }
  }

  // ---- tail: dump h(T-1) (slot 31 WGs, one per batch) ----
  if (slot == 31 && (tid >> 8) == (b_g & 1)) {
    const u64* hb = hg64 + (size_t)((T_ + 1) & 1) * WPS;
    const int idx = (b_g >> 1) * NTH + tid;
    u64 v = agload64(&hb[idx]);
    while (((u32)v & 3u) != ((u32)T_ & 3u)) {
      __builtin_amdgcn_s_sleep(1);
      v = agload64(&hb[idx]);
    }
    hs[((size_t)(T_ - 1) * B_ + b_g) * 256 + (tid & 255)] = v;
  }
}

// ---- deferred logits + softmax + NLL: one WG per timestep, all 8 batches.
// W1 row-per-thread, register-blocked over the 8 batches (W1 read once/WG).
__global__ __launch_bounds__(256, 4)
void loss_kernel(const int* __restrict__ ys, const float* __restrict__ b1,
                 const float* __restrict__ W1, const u64* __restrict__ hs,
                 float* __restrict__ partials) {
  __shared__ float hs_s[B_][H_];      // 32 KB
  __shared__ float logits_s[B_][V_];  //  8 KB
  const int tau = blockIdx.x;
  const int tid = threadIdx.x;

  #pragma unroll
  for (int b = 0; b < B_; ++b)
    *(float4*)&hs_s[b][tid * 4] = dec4(hs[((size_t)tau * B_ + b) * 256 + tid]);
  __syncthreads();

  const float* wrow = &W1[(size_t)tid * H_];
  float4 a[B_];
  #pragma unroll
  for (int b = 0; b < B_; ++b) a[b] = make_float4(0.f, 0.f, 0.f, 0.f);
  #pragma unroll 4
  for (int k = 0; k < 256; ++k) {
    const float4 w4 = *(const float4*)&wrow[k * 4];
    #pragma unroll
    for (int b = 0; b < B_; ++b) {
      const float4 h4 = *(const float4*)&hs_s[b][k * 4];   // LDS broadcast
      a[b].x = fmaf(w4.x, h4.x, a[b].x);
      a[b].y = fmaf(w4.y, h4.y, a[b].y);
      a[b].z = fmaf(w4.z, h4.z, a[b].z);
      a[b].w = fmaf(w4.w, h4.w, a[b].w);
    }
  }
  const float bb = b1[tid];
  #pragma unroll
  for (int b = 0; b < B_; ++b)
    logits_s[b][tid] = (a[b].x + a[b].y) + (a[b].z + a[b].w) + bb;
  __syncthreads();

  // wave w reduces batches w and 4+w
  const int wv = tid >> 6, lane = tid & 63;
  float acc = 0.f;
  #pragma unroll
  for (int h = 0; h < 2; ++h) {
    const int b = wv + h * 4;
    const float* lg = logits_s[b];
    float mx = fmaxf(fmaxf(lg[lane * 4], lg[lane * 4 + 1]),
                     fmaxf(lg[lane * 4 + 2], lg[lane * 4 + 3]));
    #pragma unroll
    for (int m = 1; m < 64; m <<= 1) mx = fmaxf(mx, __shfl_xor(mx, m, 64));
    float se = __expf(lg[lane * 4] - mx) + __expf(lg[lane * 4 + 1] - mx) +
               __expf(lg[lane * 4 + 2] - mx) + __expf(lg[lane * 4 + 3] - mx);
    #pragma unroll
    for (int m = 1; m < 64; m <<= 1) se += __shfl_xor(se, m, 64);
    if (lane == 0) acc += -(lg[ys[b * T_ + tau]] - mx - __logf(se));
  }
  __shared__ float pacc[4];
  if (lane == 0) pacc[wv] = acc;
  __syncthreads();
  if (tid == 0) partials[tau] = (pacc[0] + pacc[1]) + (pacc[2] + pacc[3]);
}

// ---- final mean: single WG, deterministic, no atomics ----
__global__ __launch_bounds__(256, 1)
void reduce_kernel(const float* __restrict__ partials, float* __restrict__ out) {
  const int tid = threadIdx.x;
  float acc = 0.f;
  #pragma unroll
  for (int i = 0; i < T_ / 256; ++i) acc += partials[i * 256 + tid];
  #pragma unroll
  for (int m = 1; m < 64; m <<= 1) acc += __shfl_xor(acc, m, 64);
  __shared__ float w[4];
  if ((tid & 63) == 0) w[tid >> 6] = acc;
  __syncthreads();
  if (tid == 0) out[0] = ((w[0] + w[1]) + (w[2] + w[3])) * (1.0f / (B_ * T_));
}

extern "C" void kernel_launch(void* const* d_in, const int* in_sizes, int n_in,
                              void* d_out, int out_size, void* d_ws, size_t ws_size,
                              hipStream_t stream) {
  const int*   Xs   = (const int*)d_in[0];
  const int*   ys   = (const int*)d_in[1];
  // d_in[2] = predict (always 0)
  const float* W_ih = (const float*)d_in[3];
  const float* W_hh = (const float*)d_in[4];
  const float* b_ih = (const float*)d_in[5];
  const float* b_hh = (const float*)d_in[6];
  const float* W1   = (const float*)d_in[7];
  const float* b1   = (const float*)d_in[8];
  float* out = (float*)d_out;

  u64*   hg64     = (u64*)((char*)d_ws + OFF_TRANS);
  float* partials = (float*)((char*)d_ws + OFF_PART);
  u64*   hs       = (u64*)((char*)d_ws + OFF_HS);

  // replay-safe: zero transport tags (tag0 == h(-1)=0)
  hipMemsetAsync(hg64, 0, 2 * WPS * sizeof(u64), stream);

  void* args[] = { (void*)&Xs, (void*)&W_ih, (void*)&W_hh, (void*)&b_ih,
                   (void*)&b_hh, (void*)&hg64, (void*)&hs };
  hipError_t e = hipLaunchCooperativeKernel((const void*)charrnn_lstm, dim3(NWG),
                                            dim3(NTH), args, 0, stream);
  if (e != hipSuccess) {
    hipLaunchKernelGGL(charrnn_lstm, dim3(NWG), dim3(NTH), 0, stream,
                       Xs, W_ih, W_hh, b_ih, b_hh, hg64, hs);
  }

  loss_kernel<<<T_, 256, 0, stream>>>(ys, b1, W1, hs, partials);
  reduce_kernel<<<1, 256, 0, stream>>>(partials, out);
}